// Round 9
// baseline (148.626 us; speedup 1.0000x reference)
//
#include <hip/hip_runtime.h>
#include <hip/hip_cooperative_groups.h>

namespace cg = cooperative_groups;

#define NQ 8
#define BINS 256
#define D 128
#define RPB 32            // rows per block
#define THREADS 512       // 8 waves; grid = 256 -> 1 block/CU
#define FREG 520          // shorts per frag region (512 + 8 pad)

typedef short s8v __attribute__((ext_vector_type(8)));   // 8 bf16 in 4 VGPRs
typedef float f4v __attribute__((ext_vector_type(4)));   // MFMA accumulator

static __device__ __forceinline__ unsigned short bf16_rtne(float x) {
    unsigned u = __float_as_uint(x);
    unsigned r = (u + 0x7fffu + ((u >> 16) & 1u)) >> 16;
    return (unsigned short)r;
}
static __device__ __forceinline__ float bf16_to_f(unsigned short h) {
    return __uint_as_float(((unsigned)h) << 16);
}
struct Split3 { short h, m, l; };
static __device__ __forceinline__ Split3 split3(float x) {
    Split3 s;
    unsigned short hb = bf16_rtne(x);
    float r1 = x - bf16_to_f(hb);
    unsigned short mb = bf16_rtne(r1);
    unsigned short lb = bf16_rtne(r1 - bf16_to_f(mb));
    s.h = (short)hb; s.m = (short)mb; s.l = (short)lb;
    return s;
}
static __device__ __forceinline__ unsigned long long shfl_xor_u64(unsigned long long v, int mask) {
    int lo = (int)(unsigned)(v & 0xffffffffull);
    int hi = (int)(unsigned)(v >> 32);
    lo = __shfl_xor(lo, mask, 64);
    hi = __shfl_xor(hi, mask, 64);
    return ((unsigned long long)(unsigned)hi << 32) | (unsigned)lo;
}
static __device__ __forceinline__ unsigned long long u64min(unsigned long long a, unsigned long long b) {
    return a < b ? a : b;
}

// frag store: thread owns (row rr_ 0..31, kchunk g8 0..15); R7's proven mapping
static __device__ __forceinline__ void frag_store(
    const float* rres, short* ah, short* am, short* al, int rr_, int g8)
{
    s8v h8, m8, l8;
    #pragma unroll
    for (int j = 0; j < 8; ++j) {
        Split3 sp = split3(rres[j]);
        h8[j] = sp.h; m8[j] = sp.m; l8[j] = sp.l;
    }
    int q = g8 & 3;
    int reg = (rr_ >> 4) * 4 + (g8 >> 2);          // mt*4 + ks
    int idx16 = q * 16 + (((rr_ & 15) + 4 * q) & 15);
    int off = reg * FREG + idx16 * 8;
    *(s8v*)&ah[off] = h8;
    *(s8v*)&am[off] = m8;
    *(s8v*)&al[off] = l8;
}

__global__ __launch_bounds__(THREADS, 2) void rvq_fused(
    const float* __restrict__ hidden,     // [N, D]
    const float* __restrict__ cb_f32,     // [NQ, BINS, D]
    short* __restrict__ cb_hi,            // ws: swizzled bf16 splits
    short* __restrict__ cb_mid,
    short* __restrict__ cb_lo,
    float* __restrict__ c2p,              // ws: [NQ, BINS]
    float* __restrict__ out_codes,        // [NQ, N] as float
    float* __restrict__ out_quant,        // [N, D]
    int N)
{
    __shared__ short ah[8 * FREG];
    __shared__ short am[8 * FREG];
    __shared__ short al[8 * FREG];
    __shared__ unsigned long long redw[RPB][8];

    const int t = threadIdx.x;
    const int w = t >> 6;                 // wave 0..7
    const int l = t & 63;
    const int quad = l >> 4;
    const int m = l & 15;
    const int row0 = blockIdx.x * RPB;
    const int woff = w * 32;              // this wave's 32-bin window
    const int rr_ = t >> 4;               // owned row 0..31
    const int g8 = t & 15;                // owned k-chunk

    // ================= phase A: prep (one task = one (level,bin) per wave) ==========
    {
        const int task = blockIdx.x * 8 + w;       // 256 blocks x 8 waves = 2048 tasks
        const int L = task >> 8;
        const int bin = task & 255;
        if (l < 16) {                              // lane = kchunk 0..15
            const float4* src = (const float4*)(cb_f32 + ((size_t)L * BINS + bin) * D) + l * 2;
            float4 v0 = src[0], v1 = src[1];
            float xs[8] = {v0.x, v0.y, v0.z, v0.w, v1.x, v1.y, v1.z, v1.w};
            s8v h8, m8, l8;
            float s = 0.f;
            #pragma unroll
            for (int j = 0; j < 8; ++j) {
                Split3 sp = split3(xs[j]);
                h8[j] = sp.h; m8[j] = sp.m; l8[j] = sp.l;
                s = fmaf(xs[j], xs[j], s);
            }
            int idx = (L * 16 + l) * BINS + bin;
            ((s8v*)cb_hi)[idx]  = h8;
            ((s8v*)cb_mid)[idx] = m8;
            ((s8v*)cb_lo)[idx]  = l8;
            // same 16-lane tree as R7 prep (bit-identical c2)
            s += __shfl_xor(s, 1, 64);
            s += __shfl_xor(s, 2, 64);
            s += __shfl_xor(s, 4, 64);
            s += __shfl_xor(s, 8, 64);
            if (l == 0) c2p[L * BINS + bin] = s;
        }
    }
    cg::this_grid().sync();

    // ================= phase B: main ==================================================
    const s8v* bhp = (const s8v*)cb_hi;
    const s8v* bmp = (const s8v*)cb_mid;
    const s8v* blp = (const s8v*)cb_lo;

    float rres[8];
    {
        const float4* hp = (const float4*)(hidden + (size_t)(row0 + rr_) * D + g8 * 8);
        float4 v0 = hp[0], v1 = hp[1];
        rres[0] = v0.x; rres[1] = v0.y; rres[2] = v0.z; rres[3] = v0.w;
        rres[4] = v1.x; rres[5] = v1.y; rres[6] = v1.z; rres[7] = v1.w;
    }
    frag_store(rres, ah, am, al, rr_, g8);

    // bootstrap B prefetch for level 0 (both nt windows)
    s8v bh[2][4], bm[2][4], bl[2][4];
    float c2v[2];
    #pragma unroll
    for (int nt = 0; nt < 2; ++nt) {
        int bin = woff + nt * 16 + m;
        c2v[nt] = c2p[bin];                        // level 0
        #pragma unroll
        for (int ks = 0; ks < 4; ++ks) {
            int idx = (ks * 4 + quad) * BINS + bin;
            bh[nt][ks] = bhp[idx];
            bm[nt][ks] = bmp[idx];
            bl[nt][ks] = blp[idx];
        }
    }

    for (int level = 0; level < NQ; ++level) {
        __syncthreads();   // barrier1: A-frag writes visible

        // A fragments (R7's swizzled read, conflict-balanced)
        s8v afh[2][4], afm[2][4], afl[2][4];
        const int idx16 = quad * 16 + ((m + 4 * quad) & 15);
        #pragma unroll
        for (int mt = 0; mt < 2; ++mt)
            #pragma unroll
            for (int ks = 0; ks < 4; ++ks) {
                int off = (mt * 4 + ks) * FREG + idx16 * 8;
                afh[mt][ks] = *(const s8v*)&ah[off];
                afm[mt][ks] = *(const s8v*)&am[off];
                afl[mt][ks] = *(const s8v*)&al[off];
            }

        unsigned long long best[2][4];
        #pragma unroll
        for (int mt = 0; mt < 2; ++mt)
            #pragma unroll
            for (int i = 0; i < 4; ++i) best[mt][i] = ~0ull;

        #pragma unroll
        for (int nt = 0; nt < 2; ++nt) {
            const int bin = woff + nt * 16 + m;
            #pragma unroll
            for (int mt = 0; mt < 2; ++mt) {
                // single accumulator: hh + hm + mh + mm + hl + lh all chained
                f4v a0 = {0.f, 0.f, 0.f, 0.f};
                #pragma unroll
                for (int ks = 0; ks < 4; ++ks) {
                    a0 = __builtin_amdgcn_mfma_f32_16x16x32_bf16(afh[mt][ks], bh[nt][ks], a0, 0, 0, 0);
                    a0 = __builtin_amdgcn_mfma_f32_16x16x32_bf16(afh[mt][ks], bm[nt][ks], a0, 0, 0, 0);
                    a0 = __builtin_amdgcn_mfma_f32_16x16x32_bf16(afm[mt][ks], bh[nt][ks], a0, 0, 0, 0);
                    a0 = __builtin_amdgcn_mfma_f32_16x16x32_bf16(afm[mt][ks], bm[nt][ks], a0, 0, 0, 0);
                    a0 = __builtin_amdgcn_mfma_f32_16x16x32_bf16(afh[mt][ks], bl[nt][ks], a0, 0, 0, 0);
                    a0 = __builtin_amdgcn_mfma_f32_16x16x32_bf16(afl[mt][ks], bh[nt][ks], a0, 0, 0, 0);
                }
                #pragma unroll
                for (int i = 0; i < 4; ++i) {
                    float k = fmaf(-2.f, a0[i], c2v[nt]);
                    unsigned u = __float_as_uint(k);
                    u = (u & 0x80000000u) ? ~u : (u | 0x80000000u);
                    unsigned long long key = ((unsigned long long)u << 32) | (unsigned)bin;
                    best[mt][i] = u64min(best[mt][i], key);
                }
            }
        }

        // argmin within 16-lane groups; stash per-wave
        #pragma unroll
        for (int mt = 0; mt < 2; ++mt)
            #pragma unroll
            for (int i = 0; i < 4; ++i) {
                unsigned long long p = best[mt][i];
                p = u64min(p, shfl_xor_u64(p, 1));
                p = u64min(p, shfl_xor_u64(p, 2));
                p = u64min(p, shfl_xor_u64(p, 4));
                p = u64min(p, shfl_xor_u64(p, 8));
                if (m == 0) redw[mt * 16 + quad * 4 + i][w] = p;
            }

        // ---- prefetch next level's B while argmin barrier + update run ----
        if (level + 1 < NQ) {
            #pragma unroll
            for (int nt = 0; nt < 2; ++nt) {
                int bin = woff + nt * 16 + m;
                c2v[nt] = c2p[(level + 1) * BINS + bin];
                #pragma unroll
                for (int ks = 0; ks < 4; ++ks) {
                    int idx = ((level + 1) * 16 + ks * 4 + quad) * BINS + bin;
                    bh[nt][ks] = bhp[idx];
                    bm[nt][ks] = bmp[idx];
                    bl[nt][ks] = blp[idx];
                }
            }
        }
        __syncthreads();   // barrier2: redw visible

        // every thread reduces its own row's 8 wave-results (broadcast reads)
        unsigned long long mn = redw[rr_][0];
        #pragma unroll
        for (int j = 1; j < 8; ++j) mn = u64min(mn, redw[rr_][j]);
        const int wb = (int)(mn & 0xffffffffull);
        if (g8 == 0)
            out_codes[(size_t)level * N + row0 + rr_] = (float)wb;

        // fp32 residual update in registers (elementwise, matches reference)
        {
            const float4* cp = (const float4*)(cb_f32 + ((size_t)level * BINS + wb) * D + g8 * 8);
            float4 c0 = cp[0], c1 = cp[1];
            rres[0] -= c0.x; rres[1] -= c0.y; rres[2] -= c0.z; rres[3] -= c0.w;
            rres[4] -= c1.x; rres[5] -= c1.y; rres[6] -= c1.z; rres[7] -= c1.w;
        }
        frag_store(rres, ah, am, al, rr_, g8);
    }

    // epilogue: quantized = hidden - residual
    {
        const float4* hp = (const float4*)(hidden + (size_t)(row0 + rr_) * D + g8 * 8);
        float4 v0 = hp[0], v1 = hp[1];
        float4 q0, q1;
        q0.x = v0.x - rres[0]; q0.y = v0.y - rres[1]; q0.z = v0.z - rres[2]; q0.w = v0.w - rres[3];
        q1.x = v1.x - rres[4]; q1.y = v1.y - rres[5]; q1.z = v1.z - rres[6]; q1.w = v1.w - rres[7];
        float4* op = (float4*)(out_quant + (size_t)(row0 + rr_) * D + g8 * 8);
        op[0] = q0; op[1] = q1;
    }
}

extern "C" void kernel_launch(void* const* d_in, const int* in_sizes, int n_in,
                              void* d_out, int out_size, void* d_ws, size_t ws_size,
                              hipStream_t stream) {
    const float* hidden    = (const float*)d_in[0];
    const float* codebooks = (const float*)d_in[1];
    float* out = (float*)d_out;
    int N = in_sizes[0] / D;                       // 8192
    float* out_codes = out;                        // [NQ, N]
    float* out_quant = out + (size_t)NQ * N;       // [N, D]

    char* ws = (char*)d_ws;
    short* cb_hi  = (short*)ws;                    // 512 KB
    short* cb_mid = (short*)(ws +  512 * 1024);    // 512 KB
    short* cb_lo  = (short*)(ws + 1024 * 1024);    // 512 KB
    float* c2     = (float*)(ws + 1536 * 1024);    // 8 KB

    void* args[] = {(void*)&hidden, (void*)&codebooks, (void*)&cb_hi, (void*)&cb_mid,
                    (void*)&cb_lo, (void*)&c2, (void*)&out_codes, (void*)&out_quant, (void*)&N};
    hipLaunchCooperativeKernel((const void*)rvq_fused, dim3(N / RPB), dim3(THREADS),
                               args, 0, stream);
}

// Round 10
// 120.589 us; speedup vs baseline: 1.2325x; 1.2325x over previous
//
#include <hip/hip_runtime.h>

#define NQ 8
#define BINS 256
#define D 128
#define RPB 32            // rows per block
#define THREADS 512       // 8 waves; grid = 256 -> 1 block/CU
#define FREG 520          // shorts per frag region (512 + 8 pad)

typedef short s8v __attribute__((ext_vector_type(8)));   // 8 bf16 in 4 VGPRs
typedef float f4v __attribute__((ext_vector_type(4)));   // MFMA accumulator

static __device__ __forceinline__ unsigned short bf16_rtne(float x) {
    unsigned u = __float_as_uint(x);
    unsigned r = (u + 0x7fffu + ((u >> 16) & 1u)) >> 16;
    return (unsigned short)r;
}
static __device__ __forceinline__ float bf16_to_f(unsigned short h) {
    return __uint_as_float(((unsigned)h) << 16);
}
struct Split3 { short h, m, l; };
static __device__ __forceinline__ Split3 split3(float x) {
    Split3 s;
    unsigned short hb = bf16_rtne(x);
    float r1 = x - bf16_to_f(hb);
    unsigned short mb = bf16_rtne(r1);
    unsigned short lb = bf16_rtne(r1 - bf16_to_f(mb));
    s.h = (short)hb; s.m = (short)mb; s.l = (short)lb;
    return s;
}
static __device__ __forceinline__ unsigned long long shfl_xor_u64(unsigned long long v, int mask) {
    int lo = (int)(unsigned)(v & 0xffffffffull);
    int hi = (int)(unsigned)(v >> 32);
    lo = __shfl_xor(lo, mask, 64);
    hi = __shfl_xor(hi, mask, 64);
    return ((unsigned long long)(unsigned)hi << 32) | (unsigned)lo;
}
static __device__ __forceinline__ unsigned long long u64min(unsigned long long a, unsigned long long b) {
    return a < b ? a : b;
}

// frag store: thread owns (row rr_ 0..31, kchunk g8 0..15); R7's proven mapping
static __device__ __forceinline__ void frag_store(
    const float* rres, short* ah, short* am, short* al, int rr_, int g8)
{
    s8v h8, m8, l8;
    #pragma unroll
    for (int j = 0; j < 8; ++j) {
        Split3 sp = split3(rres[j]);
        h8[j] = sp.h; m8[j] = sp.m; l8[j] = sp.l;
    }
    int q = g8 & 3;
    int reg = (rr_ >> 4) * 4 + (g8 >> 2);          // mt*4 + ks
    int idx16 = q * 16 + (((rr_ & 15) + 4 * q) & 15);
    int off = reg * FREG + idx16 * 8;
    *(s8v*)&ah[off] = h8;
    *(s8v*)&am[off] = m8;
    *(s8v*)&al[off] = l8;
}

// convert one 16-bin B window: fp32 float4 pairs -> split regs + ||c||^2
static __device__ __forceinline__ float conv_window(
    const float4* v0, const float4* v1, s8v* bh, s8v* bm, s8v* bl)
{
    float s = 0.f;
    #pragma unroll
    for (int ks = 0; ks < 4; ++ks) {
        float xs[8] = {v0[ks].x, v0[ks].y, v0[ks].z, v0[ks].w,
                       v1[ks].x, v1[ks].y, v1[ks].z, v1[ks].w};
        s8v h8, m8, l8;
        #pragma unroll
        for (int j = 0; j < 8; ++j) {
            Split3 sp = split3(xs[j]);
            h8[j] = sp.h; m8[j] = sp.m; l8[j] = sp.l;
            s = fmaf(xs[j], xs[j], s);
        }
        bh[ks] = h8; bm[ks] = m8; bl[ks] = l8;
    }
    // lane holds 4 kchunks (quad, 4+quad, 8+quad, 12+quad); sum across quads
    s += __shfl_xor(s, 16, 64);
    s += __shfl_xor(s, 32, 64);
    return s;
}

__global__ __launch_bounds__(THREADS, 2) void rvq_kernel(
    const float* __restrict__ hidden,     // [N, D]
    const float* __restrict__ cb_f32,     // [NQ, BINS, D]
    float* __restrict__ out_codes,        // [NQ, N] as float
    float* __restrict__ out_quant,        // [N, D]
    int N)
{
    __shared__ short ah[8 * FREG];
    __shared__ short am[8 * FREG];
    __shared__ short al[8 * FREG];
    __shared__ unsigned long long redw[RPB][8];

    const int t = threadIdx.x;
    const int w = t >> 6;                 // wave 0..7
    const int l = t & 63;
    const int quad = l >> 4;
    const int m = l & 15;
    const int row0 = blockIdx.x * RPB;
    const int woff = w * 32;              // this wave's 32-bin window
    const int rr_ = t >> 4;               // owned row 0..31
    const int g8 = t & 15;                // owned k-chunk

    float rres[8];
    {
        const float4* hp = (const float4*)(hidden + (size_t)(row0 + rr_) * D + g8 * 8);
        float4 v0 = hp[0], v1 = hp[1];
        rres[0] = v0.x; rres[1] = v0.y; rres[2] = v0.z; rres[3] = v0.w;
        rres[4] = v1.x; rres[5] = v1.y; rres[6] = v1.z; rres[7] = v1.w;
    }
    frag_store(rres, ah, am, al, rr_, g8);

    for (int level = 0; level < NQ; ++level) {
        // ---- issue nt=0 fp32 B loads before the barrier (fly during drain) ----
        const int bin0 = woff + m;
        const int bin1 = woff + 16 + m;
        const float* b0base = cb_f32 + ((size_t)level * BINS + bin0) * D + quad * 8;
        const float* b1base = cb_f32 + ((size_t)level * BINS + bin1) * D + quad * 8;
        float4 v00[4], v01[4];
        #pragma unroll
        for (int ks = 0; ks < 4; ++ks) {
            const float4* p = (const float4*)(b0base + ks * 32);
            v00[ks] = p[0]; v01[ks] = p[1];
        }

        __syncthreads();   // barrier1: A-frag writes visible

        // ---- A fragments (swizzled read, conflict-balanced) ----
        s8v afh[2][4], afm[2][4], afl[2][4];
        const int idx16 = quad * 16 + ((m + 4 * quad) & 15);
        #pragma unroll
        for (int mt = 0; mt < 2; ++mt)
            #pragma unroll
            for (int ks = 0; ks < 4; ++ks) {
                int off = (mt * 4 + ks) * FREG + idx16 * 8;
                afh[mt][ks] = *(const s8v*)&ah[off];
                afm[mt][ks] = *(const s8v*)&am[off];
                afl[mt][ks] = *(const s8v*)&al[off];
            }

        // ---- convert nt=0 window; then issue nt=1 loads (covered by nt=0 MFMA) ----
        s8v bh0[4], bm0[4], bl0[4];
        float c20 = conv_window(v00, v01, bh0, bm0, bl0);

        float4 v10[4], v11[4];
        #pragma unroll
        for (int ks = 0; ks < 4; ++ks) {
            const float4* p = (const float4*)(b1base + ks * 32);
            v10[ks] = p[0]; v11[ks] = p[1];
        }

        unsigned long long best[2][4];
        #pragma unroll
        for (int mt = 0; mt < 2; ++mt)
            #pragma unroll
            for (int i = 0; i < 4; ++i) best[mt][i] = ~0ull;

        // ---- nt=0: MFMA (3 independent chains, R7 form) ----
        #pragma unroll
        for (int mt = 0; mt < 2; ++mt) {
            f4v a0 = {0.f, 0.f, 0.f, 0.f};   // hh
            f4v a1 = {0.f, 0.f, 0.f, 0.f};   // hm + mh
            f4v a2 = {0.f, 0.f, 0.f, 0.f};   // mm + hl + lh
            #pragma unroll
            for (int ks = 0; ks < 4; ++ks) {
                a0 = __builtin_amdgcn_mfma_f32_16x16x32_bf16(afh[mt][ks], bh0[ks], a0, 0, 0, 0);
                a1 = __builtin_amdgcn_mfma_f32_16x16x32_bf16(afh[mt][ks], bm0[ks], a1, 0, 0, 0);
                a1 = __builtin_amdgcn_mfma_f32_16x16x32_bf16(afm[mt][ks], bh0[ks], a1, 0, 0, 0);
                a2 = __builtin_amdgcn_mfma_f32_16x16x32_bf16(afm[mt][ks], bm0[ks], a2, 0, 0, 0);
                a2 = __builtin_amdgcn_mfma_f32_16x16x32_bf16(afh[mt][ks], bl0[ks], a2, 0, 0, 0);
                a2 = __builtin_amdgcn_mfma_f32_16x16x32_bf16(afl[mt][ks], bh0[ks], a2, 0, 0, 0);
            }
            #pragma unroll
            for (int i = 0; i < 4; ++i) {
                float dot = a0[i] + (a1[i] + a2[i]);
                float k = fmaf(-2.f, dot, c20);
                unsigned u = __float_as_uint(k);
                u = (u & 0x80000000u) ? ~u : (u | 0x80000000u);
                best[mt][i] = u64min(best[mt][i],
                    ((unsigned long long)u << 32) | (unsigned)bin0);
            }
        }

        // ---- nt=1: convert then MFMA ----
        s8v bh1[4], bm1[4], bl1[4];
        float c21 = conv_window(v10, v11, bh1, bm1, bl1);

        #pragma unroll
        for (int mt = 0; mt < 2; ++mt) {
            f4v a0 = {0.f, 0.f, 0.f, 0.f};
            f4v a1 = {0.f, 0.f, 0.f, 0.f};
            f4v a2 = {0.f, 0.f, 0.f, 0.f};
            #pragma unroll
            for (int ks = 0; ks < 4; ++ks) {
                a0 = __builtin_amdgcn_mfma_f32_16x16x32_bf16(afh[mt][ks], bh1[ks], a0, 0, 0, 0);
                a1 = __builtin_amdgcn_mfma_f32_16x16x32_bf16(afh[mt][ks], bm1[ks], a1, 0, 0, 0);
                a1 = __builtin_amdgcn_mfma_f32_16x16x32_bf16(afm[mt][ks], bh1[ks], a1, 0, 0, 0);
                a2 = __builtin_amdgcn_mfma_f32_16x16x32_bf16(afm[mt][ks], bm1[ks], a2, 0, 0, 0);
                a2 = __builtin_amdgcn_mfma_f32_16x16x32_bf16(afh[mt][ks], bl1[ks], a2, 0, 0, 0);
                a2 = __builtin_amdgcn_mfma_f32_16x16x32_bf16(afl[mt][ks], bh1[ks], a2, 0, 0, 0);
            }
            #pragma unroll
            for (int i = 0; i < 4; ++i) {
                float dot = a0[i] + (a1[i] + a2[i]);
                float k = fmaf(-2.f, dot, c21);
                unsigned u = __float_as_uint(k);
                u = (u & 0x80000000u) ? ~u : (u | 0x80000000u);
                best[mt][i] = u64min(best[mt][i],
                    ((unsigned long long)u << 32) | (unsigned)bin1);
            }
        }

        // ---- argmin within 16-lane groups; stash per-wave ----
        #pragma unroll
        for (int mt = 0; mt < 2; ++mt)
            #pragma unroll
            for (int i = 0; i < 4; ++i) {
                unsigned long long p = best[mt][i];
                p = u64min(p, shfl_xor_u64(p, 1));
                p = u64min(p, shfl_xor_u64(p, 2));
                p = u64min(p, shfl_xor_u64(p, 4));
                p = u64min(p, shfl_xor_u64(p, 8));
                if (m == 0) redw[mt * 16 + quad * 4 + i][w] = p;
            }
        __syncthreads();   // barrier2: redw visible

        // ---- every thread reduces its own row's 8 wave-results ----
        unsigned long long mn = redw[rr_][0];
        #pragma unroll
        for (int j = 1; j < 8; ++j) mn = u64min(mn, redw[rr_][j]);
        const int wb = (int)(mn & 0xffffffffull);
        if (g8 == 0)
            out_codes[(size_t)level * N + row0 + rr_] = (float)wb;

        // ---- fp32 residual update in registers (matches reference) ----
        {
            const float4* cp = (const float4*)(cb_f32 + ((size_t)level * BINS + wb) * D + g8 * 8);
            float4 c0 = cp[0], c1 = cp[1];
            rres[0] -= c0.x; rres[1] -= c0.y; rres[2] -= c0.z; rres[3] -= c0.w;
            rres[4] -= c1.x; rres[5] -= c1.y; rres[6] -= c1.z; rres[7] -= c1.w;
        }
        frag_store(rres, ah, am, al, rr_, g8);
    }

    // ---- epilogue: quantized = hidden - residual ----
    {
        const float4* hp = (const float4*)(hidden + (size_t)(row0 + rr_) * D + g8 * 8);
        float4 v0 = hp[0], v1 = hp[1];
        float4 q0, q1;
        q0.x = v0.x - rres[0]; q0.y = v0.y - rres[1]; q0.z = v0.z - rres[2]; q0.w = v0.w - rres[3];
        q1.x = v1.x - rres[4]; q1.y = v1.y - rres[5]; q1.z = v1.z - rres[6]; q1.w = v1.w - rres[7];
        float4* op = (float4*)(out_quant + (size_t)(row0 + rr_) * D + g8 * 8);
        op[0] = q0; op[1] = q1;
    }
}

extern "C" void kernel_launch(void* const* d_in, const int* in_sizes, int n_in,
                              void* d_out, int out_size, void* d_ws, size_t ws_size,
                              hipStream_t stream) {
    const float* hidden    = (const float*)d_in[0];
    const float* codebooks = (const float*)d_in[1];
    float* out = (float*)d_out;
    const int N = in_sizes[0] / D;                 // 8192
    float* out_codes = out;                        // [NQ, N]
    float* out_quant = out + (size_t)NQ * N;       // [N, D]

    rvq_kernel<<<dim3(N / RPB), THREADS, 0, stream>>>(
        hidden, codebooks, out_codes, out_quant, N);
}

// Round 11
// 113.901 us; speedup vs baseline: 1.3049x; 1.0587x over previous
//
#include <hip/hip_runtime.h>

#define NQ 8
#define BINS 256
#define D 128
#define RPB 32            // rows per block
#define THREADS 1024      // 16 waves; grid = 256 -> 1 block/CU -> 4 waves/SIMD
#define RSTRIDE 132       // prep staging stride
#define FREG 520          // shorts per frag region (512 + 8 pad)

typedef short s8v __attribute__((ext_vector_type(8)));   // 8 bf16 in 4 VGPRs
typedef short s4v __attribute__((ext_vector_type(4)));   // 4 bf16 in 2 VGPRs
typedef float f4v __attribute__((ext_vector_type(4)));   // MFMA accumulator

static __device__ __forceinline__ unsigned short bf16_rtne(float x) {
    unsigned u = __float_as_uint(x);
    unsigned r = (u + 0x7fffu + ((u >> 16) & 1u)) >> 16;
    return (unsigned short)r;
}
static __device__ __forceinline__ float bf16_to_f(unsigned short h) {
    return __uint_as_float(((unsigned)h) << 16);
}
struct Split3 { short h, m, l; };
static __device__ __forceinline__ Split3 split3(float x) {
    Split3 s;
    unsigned short hb = bf16_rtne(x);
    float r1 = x - bf16_to_f(hb);
    unsigned short mb = bf16_rtne(r1);
    unsigned short lb = bf16_rtne(r1 - bf16_to_f(mb));
    s.h = (short)hb; s.m = (short)mb; s.l = (short)lb;
    return s;
}
static __device__ __forceinline__ unsigned long long shfl_xor_u64(unsigned long long v, int mask) {
    int lo = (int)(unsigned)(v & 0xffffffffull);
    int hi = (int)(unsigned)(v >> 32);
    lo = __shfl_xor(lo, mask, 64);
    hi = __shfl_xor(hi, mask, 64);
    return ((unsigned long long)(unsigned)hi << 32) | (unsigned)lo;
}
static __device__ __forceinline__ unsigned long long u64min(unsigned long long a, unsigned long long b) {
    return a < b ? a : b;
}

// ---- prep: identical to R7 (passed) ----
__global__ __launch_bounds__(256) void rvq_prep(
    const float* __restrict__ cb, short* __restrict__ cb_hi,
    short* __restrict__ cb_mid, short* __restrict__ cb_lo,
    float* __restrict__ c2)
{
    __shared__ float st[16 * RSTRIDE];
    const int L = blockIdx.x >> 4;
    const int o = blockIdx.x & 15;
    const int t = threadIdx.x;

    const float4* src = (const float4*)(cb + ((size_t)L * BINS + o * 16) * D);
    #pragma unroll
    for (int i = 0; i < 2; ++i) {
        int f4 = i * 256 + t;
        int row = f4 >> 5, c4 = f4 & 31;
        float4 v = src[f4];
        float* d = &st[row * RSTRIDE + c4 * 4];
        d[0] = v.x; d[1] = v.y; d[2] = v.z; d[3] = v.w;
    }
    __syncthreads();

    const int bin = t >> 4;
    const int kc  = t & 15;
    const float* p = &st[bin * RSTRIDE + kc * 8];
    s8v h8, m8, l8;
    float s = 0.f;
    #pragma unroll
    for (int j = 0; j < 8; ++j) {
        float x = p[j];
        Split3 sp = split3(x);
        h8[j] = sp.h; m8[j] = sp.m; l8[j] = sp.l;
        s = fmaf(x, x, s);
    }
    int idx = (L * 16 + kc) * BINS + (o * 16 + bin);
    ((s8v*)cb_hi)[idx]  = h8;
    ((s8v*)cb_mid)[idx] = m8;
    ((s8v*)cb_lo)[idx]  = l8;
    s += __shfl_xor(s, 1, 64);
    s += __shfl_xor(s, 2, 64);
    s += __shfl_xor(s, 4, 64);
    s += __shfl_xor(s, 8, 64);
    if (kc == 0) c2[L * BINS + o * 16 + bin] = s;
}

// frag store, 4-element half-slot: thread owns (row rr_, kchunk g8, half)
static __device__ __forceinline__ void frag_store4(
    const float* rres, short* ah, short* am, short* al, int rr_, int g8, int half)
{
    s4v h4, m4, l4;
    #pragma unroll
    for (int j = 0; j < 4; ++j) {
        Split3 sp = split3(rres[j]);
        h4[j] = sp.h; m4[j] = sp.m; l4[j] = sp.l;
    }
    int q = g8 & 3;
    int reg = (rr_ >> 4) * 4 + (g8 >> 2);          // mt*4 + ks
    int idx16 = q * 16 + (((rr_ & 15) + 4 * q) & 15);
    int off = reg * FREG + idx16 * 8 + half * 4;
    *(s4v*)&ah[off] = h4;
    *(s4v*)&am[off] = m4;
    *(s4v*)&al[off] = l4;
}

// ---- main: 32 rows, 16 waves (4/SIMD); wave = one 16-bin window, mt=2 ----
__global__ __launch_bounds__(THREADS, 4) void rvq_kernel(
    const float* __restrict__ hidden,     // [N, D]
    const float* __restrict__ cb_f32,     // [NQ, BINS, D]
    const short* __restrict__ cb_hi,
    const short* __restrict__ cb_mid,
    const short* __restrict__ cb_lo,
    const float* __restrict__ c2p,        // [NQ, BINS]
    float* __restrict__ out_codes,        // [NQ, N] as float
    float* __restrict__ out_quant,        // [N, D]
    int N)
{
    __shared__ short ah[8 * FREG];
    __shared__ short am[8 * FREG];
    __shared__ short al[8 * FREG];
    __shared__ unsigned long long redw[RPB][16];

    const int t = threadIdx.x;
    const int w = t >> 6;                 // wave 0..15
    const int l = t & 63;
    const int quad = l >> 4;
    const int m = l & 15;
    const int row0 = blockIdx.x * RPB;
    const int woff = w * 16;              // this wave's 16-bin window
    const int rr_ = t >> 5;               // owned row 0..31
    const int g4 = t & 31;                // owned dim-quarter (4 floats)
    const int g8 = g4 >> 1;               // kchunk 0..15
    const int half = g4 & 1;

    // residual: 4 floats per thread
    float rres[4];
    {
        const float4* hp = (const float4*)(hidden + (size_t)(row0 + rr_) * D + g4 * 4);
        float4 v = hp[0];
        rres[0] = v.x; rres[1] = v.y; rres[2] = v.z; rres[3] = v.w;
    }
    frag_store4(rres, ah, am, al, rr_, g8, half);

    const s8v* bhp = (const s8v*)cb_hi;
    const s8v* bmp = (const s8v*)cb_mid;
    const s8v* blp = (const s8v*)cb_lo;

    // bootstrap B prefetch for level 0
    s8v bh[4], bm[4], bl[4];
    float c2v;
    {
        int bin = woff + m;
        c2v = c2p[bin];
        #pragma unroll
        for (int ks = 0; ks < 4; ++ks) {
            int idx = (ks * 4 + quad) * BINS + bin;
            bh[ks] = bhp[idx];
            bm[ks] = bmp[idx];
            bl[ks] = blp[idx];
        }
    }

    for (int level = 0; level < NQ; ++level) {
        const int bin = woff + m;
        __syncthreads();   // barrier1: A-frag writes visible

        // A fragments (swizzled read, conflict-balanced)
        s8v afh[2][4], afm[2][4], afl[2][4];
        const int idx16 = quad * 16 + ((m + 4 * quad) & 15);
        #pragma unroll
        for (int mt = 0; mt < 2; ++mt)
            #pragma unroll
            for (int ks = 0; ks < 4; ++ks) {
                int off = (mt * 4 + ks) * FREG + idx16 * 8;
                afh[mt][ks] = *(const s8v*)&ah[off];
                afm[mt][ks] = *(const s8v*)&am[off];
                afl[mt][ks] = *(const s8v*)&al[off];
            }

        // MFMA: 3 independent chains per mt (R7 form, bit-identical)
        unsigned long long best[2][4];
        #pragma unroll
        for (int mt = 0; mt < 2; ++mt) {
            f4v a0 = {0.f, 0.f, 0.f, 0.f};   // hh
            f4v a1 = {0.f, 0.f, 0.f, 0.f};   // hm + mh
            f4v a2 = {0.f, 0.f, 0.f, 0.f};   // mm + hl + lh
            #pragma unroll
            for (int ks = 0; ks < 4; ++ks) {
                a0 = __builtin_amdgcn_mfma_f32_16x16x32_bf16(afh[mt][ks], bh[ks], a0, 0, 0, 0);
                a1 = __builtin_amdgcn_mfma_f32_16x16x32_bf16(afh[mt][ks], bm[ks], a1, 0, 0, 0);
                a1 = __builtin_amdgcn_mfma_f32_16x16x32_bf16(afm[mt][ks], bh[ks], a1, 0, 0, 0);
                a2 = __builtin_amdgcn_mfma_f32_16x16x32_bf16(afm[mt][ks], bm[ks], a2, 0, 0, 0);
                a2 = __builtin_amdgcn_mfma_f32_16x16x32_bf16(afh[mt][ks], bl[ks], a2, 0, 0, 0);
                a2 = __builtin_amdgcn_mfma_f32_16x16x32_bf16(afl[mt][ks], bh[ks], a2, 0, 0, 0);
            }
            #pragma unroll
            for (int i = 0; i < 4; ++i) {
                float dot = a0[i] + (a1[i] + a2[i]);
                float k = fmaf(-2.f, dot, c2v);
                unsigned u = __float_as_uint(k);
                u = (u & 0x80000000u) ? ~u : (u | 0x80000000u);
                best[mt][i] = ((unsigned long long)u << 32) | (unsigned)bin;
            }
        }

        // argmin within 16-lane groups; stash per-wave
        #pragma unroll
        for (int mt = 0; mt < 2; ++mt)
            #pragma unroll
            for (int i = 0; i < 4; ++i) {
                unsigned long long p = best[mt][i];
                p = u64min(p, shfl_xor_u64(p, 1));
                p = u64min(p, shfl_xor_u64(p, 2));
                p = u64min(p, shfl_xor_u64(p, 4));
                p = u64min(p, shfl_xor_u64(p, 8));
                if (m == 0) redw[mt * 16 + quad * 4 + i][w] = p;
            }

        // prefetch next level's B (flies under barrier2 + update + barrier1)
        if (level + 1 < NQ) {
            c2v = c2p[(level + 1) * BINS + bin];
            #pragma unroll
            for (int ks = 0; ks < 4; ++ks) {
                int idx = ((level + 1) * 16 + ks * 4 + quad) * BINS + bin;
                bh[ks] = bhp[idx];
                bm[ks] = bmp[idx];
                bl[ks] = blp[idx];
            }
        }
        __syncthreads();   // barrier2: redw visible

        // every thread reduces its own row's 16 wave-results (broadcast reads)
        unsigned long long mn = redw[rr_][0];
        #pragma unroll
        for (int j = 1; j < 16; ++j) mn = u64min(mn, redw[rr_][j]);
        const int wb = (int)(mn & 0xffffffffull);
        if (g4 == 0)
            out_codes[(size_t)level * N + row0 + rr_] = (float)wb;

        // fp32 residual update in registers (elementwise, matches reference)
        {
            const float4* cp = (const float4*)(cb_f32 + ((size_t)level * BINS + wb) * D + g4 * 4);
            float4 c = cp[0];
            rres[0] -= c.x; rres[1] -= c.y; rres[2] -= c.z; rres[3] -= c.w;
        }
        frag_store4(rres, ah, am, al, rr_, g8, half);
    }

    // epilogue: quantized = hidden - residual
    {
        const float4* hp = (const float4*)(hidden + (size_t)(row0 + rr_) * D + g4 * 4);
        float4 v = hp[0];
        float4 q;
        q.x = v.x - rres[0]; q.y = v.y - rres[1]; q.z = v.z - rres[2]; q.w = v.w - rres[3];
        float4* op = (float4*)(out_quant + (size_t)(row0 + rr_) * D + g4 * 4);
        op[0] = q;
    }
}

extern "C" void kernel_launch(void* const* d_in, const int* in_sizes, int n_in,
                              void* d_out, int out_size, void* d_ws, size_t ws_size,
                              hipStream_t stream) {
    const float* hidden    = (const float*)d_in[0];
    const float* codebooks = (const float*)d_in[1];
    float* out = (float*)d_out;
    const int N = in_sizes[0] / D;                 // 8192
    float* out_codes = out;                        // [NQ, N]
    float* out_quant = out + (size_t)NQ * N;       // [N, D]

    char* ws = (char*)d_ws;
    short* cb_hi  = (short*)ws;                    // 512 KB
    short* cb_mid = (short*)(ws +  512 * 1024);    // 512 KB
    short* cb_lo  = (short*)(ws + 1024 * 1024);    // 512 KB
    float* c2     = (float*)(ws + 1536 * 1024);    // 8 KB

    rvq_prep<<<dim3(NQ * 16), 256, 0, stream>>>(codebooks, cb_hi, cb_mid, cb_lo, c2);
    rvq_kernel<<<dim3(N / RPB), THREADS, 0, stream>>>(
        hidden, codebooks, cb_hi, cb_mid, cb_lo, c2, out_codes, out_quant, N);
}